// Round 3
// baseline (323.381 us; speedup 1.0000x reference)
//
#include <hip/hip_runtime.h>
#include <stdint.h>

// ---------------------------------------------------------------------------
// TSA block: out = x + softmax((h Wq)(h Wk)^T / 32) (h Wv),  h = x + pos_enc
// B=4, S=2048, D=1024. fp32 I/O, f16 MFMA internals.
// R3: transposed-operand GEMMs for vectorized epilogues; transpose_v deleted.
//   - QKV z=2 writes V^T directly (f16x4 stores)
//   - logits GEMM: A=k, Bt=q, transposed store -> logits[q][k] f16x4
//   - PV GEMM: A=vT, Bt=attn, transposed store -> out[s][d] float4 (+X float4)
// NOTE: SQ_LDS_BANK_CONFLICT ~= 8 x global_load_lds count (DMA write
// serialization, 1024B/128B-per-cyc) — inherent, not a read conflict.
// ---------------------------------------------------------------------------

#define AS1(p) ((__attribute__((address_space(1))) void*)(p))
#define AS3(p) ((__attribute__((address_space(3))) void*)(p))

typedef _Float16 f16x8 __attribute__((ext_vector_type(8)));
typedef _Float16 f16x4 __attribute__((ext_vector_type(4)));
typedef float f32x4 __attribute__((ext_vector_type(4)));

// ---------------- h = x + pe, cast to f16 ----------------------------------
__global__ __launch_bounds__(256) void make_h(const float* __restrict__ x,
                                              _Float16* __restrict__ h) {
  const size_t gid = (size_t)blockIdx.x * 256 + threadIdx.x;
  const size_t e = gid * 4;               // 4 consecutive d per thread
  const int d = (int)(e & 1023);
  const int m = (int)(e >> 10);
  const int s = m & 2047;                 // position within sequence
  const float4 xv = *(const float4*)(x + e);
  const int half = d >> 9;                // 0: sin block, 1: cos block
  const int j0 = d & 511;
  const float c = -0.017988946039016f;    // -ln(10000)/512
  float p[4];
#pragma unroll
  for (int t = 0; t < 4; t++) {
    const float r = __expf((float)(j0 + t) * c);
    const float a = (float)s * r;
    p[t] = half ? __cosf(a) : __sinf(a);
  }
  f16x4 o;
  o[0] = (_Float16)(xv.x + p[0]);
  o[1] = (_Float16)(xv.y + p[1]);
  o[2] = (_Float16)(xv.z + p[2]);
  o[3] = (_Float16)(xv.w + p[3]);
  *(f16x4*)(h + e) = o;
}

// ---------------- Wt[z][n][k] = (f16) W_z[k][n] ----------------------------
__global__ __launch_bounds__(256) void transpose_w(const float* __restrict__ Wq,
                                                   const float* __restrict__ Wk,
                                                   const float* __restrict__ Wv,
                                                   _Float16* __restrict__ Wt) {
  __shared__ float t[32][33];
  const int z = blockIdx.z;
  const float* W = (z == 0) ? Wq : (z == 1) ? Wk : Wv;
  _Float16* o = Wt + (size_t)z * 1024 * 1024;
  const int tx = threadIdx.x, ty = threadIdx.y;
  const int n0 = blockIdx.x * 32, k0 = blockIdx.y * 32;
#pragma unroll
  for (int i = ty; i < 32; i += 8)
    t[i][tx] = W[(size_t)(k0 + i) * 1024 + (n0 + tx)];
  __syncthreads();
#pragma unroll
  for (int i = ty; i < 32; i += 8)
    o[(size_t)(n0 + i) * 1024 + (k0 + tx)] = (_Float16)t[tx][i];
}

// ---------------- row softmax: f16 logits -> f16 attn ----------------------
__global__ __launch_bounds__(256) void softmax_rows(const _Float16* __restrict__ L,
                                                    _Float16* __restrict__ P) {
  const size_t row = blockIdx.x;
  const _Float16* lr = L + row * 2048;
  _Float16* pr = P + row * 2048;
  const int tid = threadIdx.x;
  const f16x8 v = *(const f16x8*)(lr + tid * 8);
  float f[8];
#pragma unroll
  for (int t = 0; t < 8; t++) f[t] = (float)v[t];
  float mx = f[0];
#pragma unroll
  for (int t = 1; t < 8; t++) mx = fmaxf(mx, f[t]);
#pragma unroll
  for (int off = 32; off > 0; off >>= 1) mx = fmaxf(mx, __shfl_xor(mx, off));
  __shared__ float redm[4];
  __shared__ float reds[4];
  const int lane = tid & 63, wave = tid >> 6;
  if (lane == 0) redm[wave] = mx;
  __syncthreads();
  mx = fmaxf(fmaxf(redm[0], redm[1]), fmaxf(redm[2], redm[3]));
  float e[8];
  float sm = 0.f;
#pragma unroll
  for (int t = 0; t < 8; t++) { e[t] = __expf(f[t] - mx); sm += e[t]; }
#pragma unroll
  for (int off = 32; off > 0; off >>= 1) sm += __shfl_xor(sm, off);
  if (lane == 0) reds[wave] = sm;
  __syncthreads();
  sm = reds[0] + reds[1] + reds[2] + reds[3];
  const float inv = 1.0f / sm;
  f16x8 o;
#pragma unroll
  for (int t = 0; t < 8; t++) o[t] = (_Float16)(e[t] * inv);
  *(f16x8*)(pr + tid * 8) = o;
}

// ---------------- m97-style 128x128 A·B^T GEMM, f16 MFMA 16x16x32 ----------
// A: [M x K] row-major f16, Bt: [N x K] row-major f16 (i.e. B^T).
// MODE 0 (QKV):   z<2: C f16 row-major [M x N] = A·B + bias(z)  -> C0 + z*sC
//                 z==2: V^T f16: C1[b][n][s] = A·B + bias, f16x4 stores
// MODE 1 (logits^T): C f16: C0[z*sC + n*ldc + m] = (A·B)[m][n] / 32, f16x4
// MODE 2 (PV^T+res): C f32: C0[z*sC + n*ldc + m] = (A·B)[m][n] + X, float4
template <int MODE>
__global__ __launch_bounds__(256) void gemm_bt(
    const _Float16* __restrict__ A0, long long sA,
    const _Float16* __restrict__ B0, long long sB,
    void* __restrict__ C0, long long sC, void* __restrict__ C1,
    const float* __restrict__ aux0, const float* __restrict__ aux1,
    const float* __restrict__ aux2, long long sX,
    const int K, const int N, const int ldc) {
  __shared__ __align__(16) _Float16 As[128 * 32];
  __shared__ __align__(16) _Float16 Bs[128 * 32];
  const int tid = threadIdx.x;
  const int z = blockIdx.z;
  const int bm0 = blockIdx.x * 128, bn0 = blockIdx.y * 128;
  const _Float16* A = A0 + (size_t)z * sA;
  const _Float16* Bt = B0 + (size_t)z * sB;

  // staging pointers: thread t loads 16B from row (t>>2), col chunk (t&3)*8
  const _Float16* a0 = A + (size_t)(bm0 + (tid >> 2)) * K + (tid & 3) * 8;
  const _Float16* a1 = a0 + (size_t)64 * K;
  const _Float16* b0 = Bt + (size_t)(bn0 + (tid >> 2)) * K + (tid & 3) * 8;
  const _Float16* b1 = b0 + (size_t)64 * K;

  const int lane = tid & 63, wave = tid >> 6;
  const int wr = wave >> 1, wc = wave & 1;   // wave -> 64x64 quadrant
  const int quad = lane >> 4, l16 = lane & 15;

  f32x4 acc[4][4];
#pragma unroll
  for (int i = 0; i < 4; i++)
#pragma unroll
    for (int j = 0; j < 4; j++) {
      f32x4 zz = {0.f, 0.f, 0.f, 0.f};
      acc[i][j] = zz;
    }

  for (int k0 = 0; k0 < K; k0 += 32) {
    __syncthreads();  // protect LDS from previous iteration's readers
    __builtin_amdgcn_global_load_lds(AS1(a0 + k0), AS3(&As[tid * 8]), 16, 0, 0);
    __builtin_amdgcn_global_load_lds(AS1(a1 + k0), AS3(&As[tid * 8 + 2048]), 16, 0, 0);
    __builtin_amdgcn_global_load_lds(AS1(b0 + k0), AS3(&Bs[tid * 8]), 16, 0, 0);
    __builtin_amdgcn_global_load_lds(AS1(b1 + k0), AS3(&Bs[tid * 8 + 2048]), 16, 0, 0);
    __syncthreads();  // drains the global_load_lds queue
    f16x8 af[4], bfr[4];
#pragma unroll
    for (int i = 0; i < 4; i++)
      af[i] = *(const f16x8*)&As[(wr * 64 + i * 16 + l16) * 32 + quad * 8];
#pragma unroll
    for (int j = 0; j < 4; j++)
      bfr[j] = *(const f16x8*)&Bs[(wc * 64 + j * 16 + l16) * 32 + quad * 8];
#pragma unroll
    for (int i = 0; i < 4; i++)
#pragma unroll
      for (int j = 0; j < 4; j++)
        acc[i][j] = __builtin_amdgcn_mfma_f32_16x16x32_f16(af[i], bfr[j],
                                                           acc[i][j], 0, 0, 0);
  }

  // epilogue: C/D layout col = lane&15 (in colb), row = quad*4 + reg
  const int rowb = bm0 + wr * 64 + quad * 4;
  const int colb = bn0 + wc * 64 + l16;
  if (MODE == 0) {
    const float* bias = (z == 0) ? aux0 : (z == 1) ? aux1 : aux2;
    if (z < 2) {
      _Float16* C = (_Float16*)C0 + (size_t)z * sC;
#pragma unroll
      for (int i = 0; i < 4; i++)
#pragma unroll
        for (int j = 0; j < 4; j++) {
          const int gn = colb + j * 16;
          const float bb = bias[gn];
#pragma unroll
          for (int r = 0; r < 4; r++)
            C[(size_t)(rowb + i * 16 + r) * N + gn] = (_Float16)(acc[i][j][r] + bb);
        }
    } else {
      // V^T: vT[b][d=gn][s], s = row - b*2048; 4 consecutive s per lane
      _Float16* VT = (_Float16*)C1;
      const int b = rowb >> 11;
      const int s0 = (rowb & 2047);
#pragma unroll
      for (int i = 0; i < 4; i++)
#pragma unroll
        for (int j = 0; j < 4; j++) {
          const int gn = colb + j * 16;
          const float bb = bias[gn];
          f16x4 o;
#pragma unroll
          for (int r = 0; r < 4; r++) o[r] = (_Float16)(acc[i][j][r] + bb);
          *(f16x4*)&VT[(size_t)b * 2097152 + (size_t)gn * 2048 + s0 + i * 16] = o;
        }
    }
  } else if (MODE == 1) {
    // C'[m][n] = logits[n][m]*32 -> store logits[n][m..m+3]/32 as f16x4
    _Float16* C = (_Float16*)C0 + (size_t)z * sC;
#pragma unroll
    for (int i = 0; i < 4; i++)
#pragma unroll
      for (int j = 0; j < 4; j++) {
        const int gn = colb + j * 16;
        f16x4 o;
#pragma unroll
        for (int r = 0; r < 4; r++) o[r] = (_Float16)(acc[i][j][r] * 0.03125f);
        *(f16x4*)&C[(size_t)gn * ldc + rowb + i * 16] = o;
      }
  } else {
    // C'[m=d][n=s] = out[s][d]; float4 store + float4 residual read
    float* C = (float*)C0 + (size_t)z * sC;
    const float* X = aux0 + (size_t)z * sX;
#pragma unroll
    for (int i = 0; i < 4; i++)
#pragma unroll
      for (int j = 0; j < 4; j++) {
        const int gn = colb + j * 16;
        const size_t base = (size_t)gn * ldc + rowb + i * 16;
        const float4 xv = *(const float4*)(X + base);
        float4 o;
        o.x = acc[i][j][0] + xv.x;
        o.y = acc[i][j][1] + xv.y;
        o.z = acc[i][j][2] + xv.z;
        o.w = acc[i][j][3] + xv.w;
        *(float4*)(C + base) = o;
      }
  }
}

// ---------------------------------------------------------------------------
extern "C" void kernel_launch(void* const* d_in, const int* in_sizes, int n_in,
                              void* d_out, int out_size, void* d_ws, size_t ws_size,
                              hipStream_t stream) {
  (void)in_sizes; (void)n_in; (void)out_size; (void)ws_size;
  const float* x  = (const float*)d_in[0];
  const float* Wq = (const float*)d_in[1];
  const float* bq = (const float*)d_in[2];
  const float* Wk = (const float*)d_in[3];
  const float* bk = (const float*)d_in[4];
  const float* Wv = (const float*)d_in[5];
  const float* bv = (const float*)d_in[6];
  float* out = (float*)d_out;
  char* ws = (char*)d_ws;

  // workspace layout (bytes):
  //   [0, 16M)      h (f16)            -- dead after QKV
  //   [16M, 22M)    Wt (f16 x3)        -- dead after QKV
  //   [22M, 38M)    q (f16)            -- dead after logits; attn overlays q+k
  //   [38M, 54M)    k (f16)
  //   [54M, 70M)    vT (f16, [b][d][s]) -- written by QKV z=2
  //   [70M, 102M)   logits (f16)
  _Float16* h      = (_Float16*)(ws);
  _Float16* Wt     = (_Float16*)(ws + 16777216);
  _Float16* qk     = (_Float16*)(ws + 23068672);
  _Float16* attn   = (_Float16*)(ws + 23068672);      // overlays q,k
  _Float16* vT     = (_Float16*)(ws + 56623104);
  _Float16* logits = (_Float16*)(ws + 73400320);

  const long long E = 8388608;  // elements per [8192 x 1024] f16 tensor

  transpose_w<<<dim3(32, 32, 3), dim3(32, 8), 0, stream>>>(Wq, Wk, Wv, Wt);
  make_h<<<8192, 256, 0, stream>>>(x, h);

  // QKV: [8192x1024] @ Wt_z; z<2 -> q,k row-major; z==2 -> vT[b][d][s]
  gemm_bt<0><<<dim3(64, 8, 3), 256, 0, stream>>>(
      h, 0LL, Wt, 1048576LL, qk, E, vT, bq, bk, bv, 0LL, 1024, 1024, 0);

  // logits^T trick: A=k_b, Bt=q_b -> store logits[b][q][k] f16, /32
  gemm_bt<1><<<dim3(16, 16, 4), 256, 0, stream>>>(
      qk + E, 2097152LL, qk, 2097152LL, logits, 4194304LL, nullptr,
      nullptr, nullptr, nullptr, 0LL, 1024, 2048, 2048);

  softmax_rows<<<8192, 256, 0, stream>>>(logits, attn);

  // PV^T trick: A=vT_b, Bt=attn_b -> out[b][s][d] = (PV)[s][d] + x, float4
  gemm_bt<2><<<dim3(8, 16, 4), 256, 0, stream>>>(
      vT, 2097152LL, attn, 4194304LL, out, 2097152LL, nullptr,
      x, nullptr, nullptr, 2097152LL, 2048, 2048, 1024);
}